// Round 1
// baseline (3453.220 us; speedup 1.0000x reference)
//
#include <hip/hip_runtime.h>
#include <cstddef>

#define kN 50000
#define kE 500000
#define kG 64
#define kDIN 64
#define kD 128
#define kH 256   // 2*D
#define kA4 512  // 4*D
#define kOUT 10
#define NPB 16   // nodes per block for dense kernels

constexpr size_t OFF_H    = 0;                           // [kN, kD] encoder h
constexpr size_t OFF_HC   = OFF_H + (size_t)kN * kD;     // [kN, kD] classifier h
constexpr size_t OFF_Z    = OFF_HC + (size_t)kN * kD;    // [kN, kD] aggregate buffer
constexpr size_t OFF_A    = OFF_Z + (size_t)kN * kD;     // [kN, kA4] att A = h@W1_top + b1
constexpr size_t OFF_B    = OFF_A + (size_t)kN * kA4;    // [kN, kA4] att B = h@W1_bot
constexpr size_t OFF_ATT  = OFF_B + (size_t)kN * kA4;    // [kE] edge weights
constexpr size_t OFF_POOL = OFF_ATT + (size_t)kE;        // [kG, kD] sums
constexpr size_t OFF_CNT  = OFF_POOL + (size_t)kG * kD;  // [kG] counts
constexpr size_t WS_TOTAL = OFF_CNT + kG;

// ~284 MB static device scratch: independent of ws_size, rewritten fully each call.
__device__ float g_ws[WS_TOTAL];

__global__ __launch_bounds__(256) void zero_range(size_t off, size_t cnt) {
    size_t i = (size_t)blockIdx.x * 256 + threadIdx.x;
    if (i < cnt) g_ws[off + i] = 0.f;
}

// h = relu(x @ eW + eb), hc = relu(x @ cW + cb); 16 nodes/block, 256 threads.
__global__ __launch_bounds__(256) void input_proj_kernel(
    const float* __restrict__ x,
    const float* __restrict__ eW, const float* __restrict__ eb,
    const float* __restrict__ cW, const float* __restrict__ cb) {
    __shared__ float xs[NPB][kDIN];
    const int node0 = blockIdx.x * NPB;
    const int t = threadIdx.x;
    for (int i = t; i < NPB * kDIN; i += 256)
        xs[i >> 6][i & 63] = x[(size_t)node0 * kDIN + i];
    __syncthreads();
    const int j = t & 127, half = t >> 7;  // 0 = encoder, 1 = classifier
    const float* W = half ? cW : eW;
    const float bias = half ? cb[j] : eb[j];
    float acc[NPB];
#pragma unroll
    for (int n = 0; n < NPB; n++) acc[n] = bias;
    for (int k = 0; k < kDIN; k++) {
        float w = W[k * kD + j];
#pragma unroll
        for (int n = 0; n < NPB; n++) acc[n] = fmaf(xs[n][k], w, acc[n]);
    }
    float* outp = g_ws + (half ? OFF_HC : OFF_H);
#pragma unroll
    for (int n = 0; n < NPB; n++)
        outp[(size_t)(node0 + n) * kD + j] = fmaxf(acc[n], 0.f);
}

// dst[row[e]] += src[col[e]] * (att[e]?); thread per (edge, d), coalesced atomics.
__global__ __launch_bounds__(256) void gin_agg_kernel(
    size_t src_off, size_t dst_off,
    const int* __restrict__ row, const int* __restrict__ col, int use_att) {
    const int idx = blockIdx.x * 256 + threadIdx.x;  // kE*kD threads, exact grid
    const int e = idx >> 7, d = idx & 127;
    const int r = row[e], c = col[e];
    float v = g_ws[src_off + (size_t)c * kD + d];
    if (use_att) v *= g_ws[OFF_ATT + e];
    atomicAdd(&g_ws[dst_off + (size_t)r * kD + d], v);
}

// h_new = [relu]( relu((z+h) @ W1 + b1) @ W2 + b2 ), in-place on h.
__global__ __launch_bounds__(256) void gin_mlp_kernel(
    size_t z_off, size_t h_off,
    const float* __restrict__ W1, const float* __restrict__ b1,
    const float* __restrict__ W2, const float* __restrict__ b2, int relu_out) {
    __shared__ float zs[NPB][kD];   // 8 KB
    __shared__ float hid[NPB][kH];  // 16 KB
    const int node0 = blockIdx.x * NPB;
    const int t = threadIdx.x;
    const float* zp = g_ws + z_off;
    float* hp = g_ws + h_off;
    for (int i = t; i < NPB * kD; i += 256) {
        size_t gi = (size_t)node0 * kD + i;
        zs[i >> 7][i & 127] = zp[gi] + hp[gi];  // z = agg + h (GIN eps=0)
    }
    __syncthreads();
    // hidden[j] for j = t (256 hidden units), 16 nodes each
    float acc[NPB];
    const float bb = b1[t];
#pragma unroll
    for (int n = 0; n < NPB; n++) acc[n] = bb;
    for (int k = 0; k < kD; k++) {
        float w = W1[k * kH + t];
#pragma unroll
        for (int n = 0; n < NPB; n++) acc[n] = fmaf(zs[n][k], w, acc[n]);
    }
#pragma unroll
    for (int n = 0; n < NPB; n++) hid[n][t] = fmaxf(acc[n], 0.f);
    __syncthreads();
    // out[d] for d = t&127; two thread-halves cover 8 nodes each
    const int d = t & 127, n0 = (t >> 7) * (NPB / 2);
    float acc2[NPB / 2];
    const float b2v = b2[d];
#pragma unroll
    for (int n = 0; n < NPB / 2; n++) acc2[n] = b2v;
    for (int m = 0; m < kH; m++) {
        float w = W2[m * kD + d];
#pragma unroll
        for (int n = 0; n < NPB / 2; n++) acc2[n] = fmaf(hid[n0 + n][m], w, acc2[n]);
    }
#pragma unroll
    for (int n = 0; n < NPB / 2; n++) {
        float v = acc2[n];
        if (relu_out) v = fmaxf(v, 0.f);
        hp[(size_t)(node0 + n0 + n) * kD + d] = v;
    }
}

// out[n, 0:512] = h[n] @ W (+ bias). W is a 128x512 slice of att_W1.
__global__ __launch_bounds__(256) void att_dense_kernel(
    size_t in_off, size_t out_off,
    const float* __restrict__ W, const float* __restrict__ bias) {
    __shared__ float zs[NPB][kD];
    const int node0 = blockIdx.x * NPB;
    const int t = threadIdx.x;
    const float* hp = g_ws + in_off;
    float* op = g_ws + out_off;
    for (int i = t; i < NPB * kD; i += 256)
        zs[i >> 7][i & 127] = hp[(size_t)node0 * kD + i];
    __syncthreads();
    float a0[NPB], a1[NPB];
    const float b0 = bias ? bias[t] : 0.f;
    const float b1v = bias ? bias[t + 256] : 0.f;
#pragma unroll
    for (int n = 0; n < NPB; n++) { a0[n] = b0; a1[n] = b1v; }
    for (int k = 0; k < kD; k++) {
        float w0 = W[k * kA4 + t], w1 = W[k * kA4 + t + 256];
#pragma unroll
        for (int n = 0; n < NPB; n++) {
            a0[n] = fmaf(zs[n][k], w0, a0[n]);
            a1[n] = fmaf(zs[n][k], w1, a1[n]);
        }
    }
#pragma unroll
    for (int n = 0; n < NPB; n++) {
        op[(size_t)(node0 + n) * kA4 + t] = a0[n];
        op[(size_t)(node0 + n) * kA4 + t + 256] = a1[n];
    }
}

// att[e] = sigmoid( relu(A[row]+B[col]) . W2 + b2 ); one 64-lane wave per edge.
__global__ __launch_bounds__(256) void att_edge_kernel(
    const int* __restrict__ row, const int* __restrict__ col,
    const float* __restrict__ W2, const float* __restrict__ b2) {
    const int e = blockIdx.x * 4 + (threadIdx.x >> 6);
    const int lane = threadIdx.x & 63;
    const float* a = g_ws + OFF_A + (size_t)row[e] * kA4;
    const float* b = g_ws + OFF_B + (size_t)col[e] * kA4;
    float s = 0.f;
#pragma unroll
    for (int i = 0; i < 8; i++) {
        int m = lane + i * 64;
        float hv = fmaxf(a[m] + b[m], 0.f);
        s = fmaf(hv, W2[m], s);
    }
    for (int off = 32; off > 0; off >>= 1) s += __shfl_down(s, off);
    if (lane == 0) {
        float logit = s + b2[0];
        g_ws[OFF_ATT + e] = 1.f / (1.f + __expf(-logit));
    }
}

__global__ __launch_bounds__(256) void pool_kernel(size_t h_off, const int* __restrict__ batch) {
    const int idx = blockIdx.x * 256 + threadIdx.x;  // kN*kD exact
    const int n = idx >> 7, d = idx & 127;
    const int g = batch[n];
    atomicAdd(&g_ws[OFF_POOL + (size_t)g * kD + d], g_ws[h_off + idx]);
    if (d == 0) atomicAdd(&g_ws[OFF_CNT + g], 1.f);
}

__global__ __launch_bounds__(640) void head_kernel(
    const float* __restrict__ hW, const float* __restrict__ hb, float* __restrict__ out) {
    const int t = threadIdx.x;  // 640 = kG*kOUT
    const int g = t / kOUT, o = t - g * kOUT;
    const float c = fmaxf(g_ws[OFF_CNT + g], 1.f);
    const float inv = 1.f / c;
    float acc = hb[o];
    for (int k = 0; k < kD; k++)
        acc = fmaf(g_ws[OFF_POOL + (size_t)g * kD + k] * inv, hW[k * kOUT + o], acc);
    out[(size_t)g * kOUT + o] = acc;
}

extern "C" void kernel_launch(void* const* d_in, const int* in_sizes, int n_in,
                              void* d_out, int out_size, void* d_ws, size_t ws_size,
                              hipStream_t stream) {
    const float* x        = (const float*)d_in[0];
    const int*   ei       = (const int*)d_in[1];
    const int*   row      = ei;
    const int*   col      = ei + kE;
    const int*   batch    = (const int*)d_in[2];
    const float* enc_in_W = (const float*)d_in[4];
    const float* enc_in_b = (const float*)d_in[5];
    const float* enc_W1   = (const float*)d_in[6];
    const float* enc_b1   = (const float*)d_in[7];
    const float* enc_W2   = (const float*)d_in[8];
    const float* enc_b2   = (const float*)d_in[9];
    const float* att_W1   = (const float*)d_in[10];
    const float* att_b1   = (const float*)d_in[11];
    const float* att_W2   = (const float*)d_in[12];
    const float* att_b2   = (const float*)d_in[13];
    const float* clf_in_W = (const float*)d_in[14];
    const float* clf_in_b = (const float*)d_in[15];
    const float* clf_W1   = (const float*)d_in[16];
    const float* clf_b1   = (const float*)d_in[17];
    const float* clf_W2   = (const float*)d_in[18];
    const float* clf_b2   = (const float*)d_in[19];
    const float* head_W   = (const float*)d_in[20];
    const float* head_b   = (const float*)d_in[21];
    float* out = (float*)d_out;

    const dim3 blk(256);

    input_proj_kernel<<<kN / NPB, blk, 0, stream>>>(x, enc_in_W, enc_in_b, clf_in_W, clf_in_b);

    // ---- encoder GIN stack ----
    for (int l = 0; l < 3; l++) {
        zero_range<<<(kN * kD) / 256, blk, 0, stream>>>(OFF_Z, (size_t)kN * kD);
        gin_agg_kernel<<<(kE * kD) / 256, blk, 0, stream>>>(OFF_H, OFF_Z, row, col, 0);
        gin_mlp_kernel<<<kN / NPB, blk, 0, stream>>>(
            OFF_Z, OFF_H,
            enc_W1 + (size_t)l * kD * kH, enc_b1 + (size_t)l * kH,
            enc_W2 + (size_t)l * kH * kD, enc_b2 + (size_t)l * kD, (l < 2) ? 1 : 0);
    }

    // ---- edge attention: A = h@W1_top + b1, B = h@W1_bot, then per-edge MLP ----
    att_dense_kernel<<<kN / NPB, blk, 0, stream>>>(OFF_H, OFF_A, att_W1, att_b1);
    att_dense_kernel<<<kN / NPB, blk, 0, stream>>>(OFF_H, OFF_B, att_W1 + (size_t)kD * kA4, nullptr);
    att_edge_kernel<<<kE / 4, blk, 0, stream>>>(row, col, att_W2, att_b2);

    // ---- classifier GIN stack (edge-weighted) ----
    for (int l = 0; l < 3; l++) {
        zero_range<<<(kN * kD) / 256, blk, 0, stream>>>(OFF_Z, (size_t)kN * kD);
        gin_agg_kernel<<<(kE * kD) / 256, blk, 0, stream>>>(OFF_HC, OFF_Z, row, col, 1);
        gin_mlp_kernel<<<kN / NPB, blk, 0, stream>>>(
            OFF_Z, OFF_HC,
            clf_W1 + (size_t)l * kD * kH, clf_b1 + (size_t)l * kH,
            clf_W2 + (size_t)l * kH * kD, clf_b2 + (size_t)l * kD, (l < 2) ? 1 : 0);
    }

    // ---- mean pool + head ----
    zero_range<<<((kG * kD + kG) + 255) / 256, blk, 0, stream>>>(OFF_POOL, (size_t)(kG * kD + kG));
    pool_kernel<<<(kN * kD) / 256, blk, 0, stream>>>(OFF_HC, batch);
    head_kernel<<<1, dim3(kG * kOUT), 0, stream>>>(head_W, head_b, out);
}

// Round 2
// 2085.326 us; speedup vs baseline: 1.6560x; 1.6560x over previous
//
#include <hip/hip_runtime.h>
#include <hip/hip_bf16.h>
#include <cstddef>

#define kN 50000
#define kE 500000
#define kG 64
#define kDIN 64
#define kD 128
#define kH 256   // 2*D
#define kA4 512  // 4*D
#define kOUT 10
#define NPB 16     // nodes per block for dense kernels
#define PCHUNK 200 // nodes per block for pooling (kN % PCHUNK == 0)

// ---- static device scratch (rewritten fully every call) ----
__device__ float g_h [(size_t)kN * kD];
__device__ float g_hc[(size_t)kN * kD];
__device__ float g_z [(size_t)kN * kD];
__device__ __attribute__((aligned(256))) __hip_bfloat16 g_A[(size_t)kN * kA4];
__device__ __attribute__((aligned(256))) __hip_bfloat16 g_B[(size_t)kN * kA4];
__device__ float g_att [kE];   // edge weights, original edge order
__device__ float g_atts[kE];   // edge weights, CSR order
__device__ int   g_rowptr[kN + 1];
__device__ int   g_cnt[kN];    // histogram, then scatter cursor
__device__ int   g_cols[kE];   // col indices in CSR order
__device__ int   g_eid [kE];   // original edge id in CSR order
__device__ float g_pool[kG * kD];
__device__ float g_gcnt[kG];

// Zero the per-call accumulators: g_cnt (histogram), g_pool, g_gcnt.
__global__ __launch_bounds__(256) void zero_prep_kernel() {
    const int i = blockIdx.x * 256 + threadIdx.x;
    if (i < kN) g_cnt[i] = 0;
    if (i < kG * kD) g_pool[i] = 0.f;
    if (i < kG) g_gcnt[i] = 0.f;
}

__global__ __launch_bounds__(256) void hist_kernel(const int* __restrict__ row) {
    const int e = blockIdx.x * 256 + threadIdx.x;
    if (e < kE) atomicAdd(&g_cnt[row[e]], 1);
}

// Single-block exclusive scan of g_cnt[0:kN] -> g_rowptr, g_cnt (cursor copy).
__global__ __launch_bounds__(1024) void scan_kernel() {
    const int t = threadIdx.x;
    const int base_i = t * 49;  // 1024*49 = 50176 >= kN
    int local[49];
    int s = 0;
    for (int i = 0; i < 49; i++) {
        const int idx = base_i + i;
        const int c = (idx < kN) ? g_cnt[idx] : 0;
        local[i] = s;  // exclusive within thread
        s += c;
    }
    __shared__ int part[1024];
    part[t] = s;
    __syncthreads();
    for (int off = 1; off < 1024; off <<= 1) {
        int v = 0;
        if (t >= off) v = part[t - off];
        __syncthreads();
        part[t] += v;
        __syncthreads();
    }
    const int base = (t == 0) ? 0 : part[t - 1];
    for (int i = 0; i < 49; i++) {
        const int idx = base_i + i;
        if (idx < kN) {
            const int v = base + local[i];
            g_rowptr[idx] = v;
            g_cnt[idx] = v;  // cursor for scatter
        }
    }
    if (t == 1023) g_rowptr[kN] = kE;
}

__global__ __launch_bounds__(256) void scatter_kernel(
    const int* __restrict__ row, const int* __restrict__ col) {
    const int e = blockIdx.x * 256 + threadIdx.x;
    if (e >= kE) return;
    const int r = row[e];
    const int pos = atomicAdd(&g_cnt[r], 1);
    g_cols[pos] = col[e];
    g_eid[pos] = e;
}

__global__ __launch_bounds__(256) void att_permute_kernel() {
    const int i = blockIdx.x * 256 + threadIdx.x;
    if (i < kE) g_atts[i] = g_att[g_eid[i]];
}

// h = relu(x @ eW + eb), hc = relu(x @ cW + cb); 16 nodes/block, 256 threads.
__global__ __launch_bounds__(256) void input_proj_kernel(
    const float* __restrict__ x,
    const float* __restrict__ eW, const float* __restrict__ eb,
    const float* __restrict__ cW, const float* __restrict__ cb) {
    __shared__ float xs[NPB][kDIN];
    const int node0 = blockIdx.x * NPB;
    const int t = threadIdx.x;
    for (int i = t; i < NPB * kDIN; i += 256)
        xs[i >> 6][i & 63] = x[(size_t)node0 * kDIN + i];
    __syncthreads();
    const int j = t & 127, half = t >> 7;  // 0 = encoder, 1 = classifier
    const float* W = half ? cW : eW;
    const float bias = half ? cb[j] : eb[j];
    float acc[NPB];
#pragma unroll
    for (int n = 0; n < NPB; n++) acc[n] = bias;
    for (int k = 0; k < kDIN; k++) {
        float w = W[k * kD + j];
#pragma unroll
        for (int n = 0; n < NPB; n++) acc[n] = fmaf(xs[n][k], w, acc[n]);
    }
    float* outp = half ? g_hc : g_h;
#pragma unroll
    for (int n = 0; n < NPB; n++)
        outp[(size_t)(node0 + n) * kD + j] = fmaxf(acc[n], 0.f);
}

// CSR aggregation, atomic-free: z[n] = h[n] + sum_{j in row n} h[col[j]] * att?
__global__ __launch_bounds__(256) void agg_csr_kernel(int src_hc, int use_att) {
    const int t = threadIdx.x;
    const int node = blockIdx.x * 2 + (t >> 7);
    const int d = t & 127;
    const float* __restrict__ src = src_hc ? g_hc : g_h;
    const int beg = g_rowptr[node], end = g_rowptr[node + 1];
    float acc = src[(size_t)node * kD + d];  // self term (GIN eps=0)
    if (use_att) {
        for (int j = beg; j < end; j++)
            acc = fmaf(src[(size_t)g_cols[j] * kD + d], g_atts[j], acc);
    } else {
        for (int j = beg; j < end; j++)
            acc += src[(size_t)g_cols[j] * kD + d];
    }
    g_z[(size_t)node * kD + d] = acc;
}

// h_new = [relu]( relu(z @ W1 + b1) @ W2 + b2 ); z already includes +h.
__global__ __launch_bounds__(256) void gin_mlp_kernel(
    int h_sel,
    const float* __restrict__ W1, const float* __restrict__ b1,
    const float* __restrict__ W2, const float* __restrict__ b2, int relu_out) {
    __shared__ float zs[NPB][kD];   // 8 KB
    __shared__ float hid[NPB][kH];  // 16 KB
    const int node0 = blockIdx.x * NPB;
    const int t = threadIdx.x;
    float* hp = h_sel ? g_hc : g_h;
    for (int i = t; i < NPB * kD; i += 256)
        zs[i >> 7][i & 127] = g_z[(size_t)node0 * kD + i];
    __syncthreads();
    float acc[NPB];
    const float bb = b1[t];
#pragma unroll
    for (int n = 0; n < NPB; n++) acc[n] = bb;
    for (int k = 0; k < kD; k++) {
        float w = W1[k * kH + t];
#pragma unroll
        for (int n = 0; n < NPB; n++) acc[n] = fmaf(zs[n][k], w, acc[n]);
    }
#pragma unroll
    for (int n = 0; n < NPB; n++) hid[n][t] = fmaxf(acc[n], 0.f);
    __syncthreads();
    const int d = t & 127, n0 = (t >> 7) * (NPB / 2);
    float acc2[NPB / 2];
    const float b2v = b2[d];
#pragma unroll
    for (int n = 0; n < NPB / 2; n++) acc2[n] = b2v;
    for (int m = 0; m < kH; m++) {
        float w = W2[m * kD + d];
#pragma unroll
        for (int n = 0; n < NPB / 2; n++) acc2[n] = fmaf(hid[n0 + n][m], w, acc2[n]);
    }
#pragma unroll
    for (int n = 0; n < NPB / 2; n++) {
        float v = acc2[n];
        if (relu_out) v = fmaxf(v, 0.f);
        hp[(size_t)(node0 + n0 + n) * kD + d] = v;
    }
}

// out[n, 0:512] = h[n] @ W (+ bias), stored bf16 into g_A (which=0) or g_B (which=1).
__global__ __launch_bounds__(256) void att_dense_kernel(
    int which, const float* __restrict__ W, const float* __restrict__ bias) {
    __shared__ float zs[NPB][kD];
    const int node0 = blockIdx.x * NPB;
    const int t = threadIdx.x;
    __hip_bfloat16* op = which ? g_B : g_A;
    for (int i = t; i < NPB * kD; i += 256)
        zs[i >> 7][i & 127] = g_h[(size_t)node0 * kD + i];
    __syncthreads();
    float a0[NPB], a1[NPB];
    const float b0 = bias ? bias[t] : 0.f;
    const float b1v = bias ? bias[t + 256] : 0.f;
#pragma unroll
    for (int n = 0; n < NPB; n++) { a0[n] = b0; a1[n] = b1v; }
    for (int k = 0; k < kD; k++) {
        float w0 = W[k * kA4 + t], w1 = W[k * kA4 + t + 256];
#pragma unroll
        for (int n = 0; n < NPB; n++) {
            a0[n] = fmaf(zs[n][k], w0, a0[n]);
            a1[n] = fmaf(zs[n][k], w1, a1[n]);
        }
    }
#pragma unroll
    for (int n = 0; n < NPB; n++) {
        op[(size_t)(node0 + n) * kA4 + t] = __float2bfloat16(a0[n]);
        op[(size_t)(node0 + n) * kA4 + t + 256] = __float2bfloat16(a1[n]);
    }
}

__device__ inline float bf_lo(unsigned int u) {
    union { unsigned int i; float f; } c; c.i = u << 16; return c.f;
}
__device__ inline float bf_hi(unsigned int u) {
    union { unsigned int i; float f; } c; c.i = u & 0xffff0000u; return c.f;
}

// att[e] = sigmoid( relu(A[row]+B[col]) . W2 + b2 ); one 64-lane wave per edge.
__global__ __launch_bounds__(256) void att_edge_kernel(
    const int* __restrict__ row, const int* __restrict__ col,
    const float* __restrict__ W2, const float* __restrict__ b2) {
    const int e = blockIdx.x * 4 + (threadIdx.x >> 6);
    const int lane = threadIdx.x & 63;
    const int m0 = lane * 8;
    const uint4 au = *(const uint4*)(g_A + (size_t)row[e] * kA4 + m0);
    const uint4 bu = *(const uint4*)(g_B + (size_t)col[e] * kA4 + m0);
    const float4 w0 = *(const float4*)(W2 + m0);
    const float4 w1 = *(const float4*)(W2 + m0 + 4);
    float s = 0.f;
    s = fmaf(fmaxf(bf_lo(au.x) + bf_lo(bu.x), 0.f), w0.x, s);
    s = fmaf(fmaxf(bf_hi(au.x) + bf_hi(bu.x), 0.f), w0.y, s);
    s = fmaf(fmaxf(bf_lo(au.y) + bf_lo(bu.y), 0.f), w0.z, s);
    s = fmaf(fmaxf(bf_hi(au.y) + bf_hi(bu.y), 0.f), w0.w, s);
    s = fmaf(fmaxf(bf_lo(au.z) + bf_lo(bu.z), 0.f), w1.x, s);
    s = fmaf(fmaxf(bf_hi(au.z) + bf_hi(bu.z), 0.f), w1.y, s);
    s = fmaf(fmaxf(bf_lo(au.w) + bf_lo(bu.w), 0.f), w1.z, s);
    s = fmaf(fmaxf(bf_hi(au.w) + bf_hi(bu.w), 0.f), w1.w, s);
    for (int off = 32; off > 0; off >>= 1) s += __shfl_down(s, off);
    if (lane == 0) {
        const float logit = s + b2[0];
        g_att[e] = 1.f / (1.f + __expf(-logit));
    }
}

// Segmented mean-pool accumulate: batch is sorted, so register-accumulate per
// thread (one dim each) and flush one atomic per graph boundary.
__global__ __launch_bounds__(128) void pool_kernel(const int* __restrict__ batch) {
    const int d = threadIdx.x;
    int n = blockIdx.x * PCHUNK;
    const int nend = n + PCHUNK;
    int gcur = batch[n];
    float acc = 0.f, cv = 0.f;
    for (; n < nend; n++) {
        const int g = batch[n];
        if (g != gcur) {
            atomicAdd(&g_pool[gcur * kD + d], acc);
            if (d == 0) atomicAdd(&g_gcnt[gcur], cv);
            acc = 0.f; cv = 0.f; gcur = g;
        }
        acc += g_hc[(size_t)n * kD + d];
        cv += 1.f;
    }
    atomicAdd(&g_pool[gcur * kD + d], acc);
    if (d == 0) atomicAdd(&g_gcnt[gcur], cv);
}

__global__ __launch_bounds__(640) void head_kernel(
    const float* __restrict__ hW, const float* __restrict__ hb,
    float* __restrict__ out) {
    const int t = threadIdx.x;  // 640 = kG*kOUT
    const int g = t / kOUT, o = t - g * kOUT;
    const float c = fmaxf(g_gcnt[g], 1.f);
    const float inv = 1.f / c;
    float acc = hb[o];
    for (int k = 0; k < kD; k++)
        acc = fmaf(g_pool[g * kD + k] * inv, hW[k * kOUT + o], acc);
    out[(size_t)g * kOUT + o] = acc;
}

extern "C" void kernel_launch(void* const* d_in, const int* in_sizes, int n_in,
                              void* d_out, int out_size, void* d_ws, size_t ws_size,
                              hipStream_t stream) {
    const float* x        = (const float*)d_in[0];
    const int*   ei       = (const int*)d_in[1];
    const int*   row      = ei;
    const int*   col      = ei + kE;
    const int*   batch    = (const int*)d_in[2];
    const float* enc_in_W = (const float*)d_in[4];
    const float* enc_in_b = (const float*)d_in[5];
    const float* enc_W1   = (const float*)d_in[6];
    const float* enc_b1   = (const float*)d_in[7];
    const float* enc_W2   = (const float*)d_in[8];
    const float* enc_b2   = (const float*)d_in[9];
    const float* att_W1   = (const float*)d_in[10];
    const float* att_b1   = (const float*)d_in[11];
    const float* att_W2   = (const float*)d_in[12];
    const float* att_b2   = (const float*)d_in[13];
    const float* clf_in_W = (const float*)d_in[14];
    const float* clf_in_b = (const float*)d_in[15];
    const float* clf_W1   = (const float*)d_in[16];
    const float* clf_b1   = (const float*)d_in[17];
    const float* clf_W2   = (const float*)d_in[18];
    const float* clf_b2   = (const float*)d_in[19];
    const float* head_W   = (const float*)d_in[20];
    const float* head_b   = (const float*)d_in[21];
    float* out = (float*)d_out;

    const dim3 blk(256);
    const int eblocks = (kE + 255) / 256;

    // ---- CSR build (reused by all 6 GIN layers) ----
    zero_prep_kernel<<<(kN + 255) / 256, blk, 0, stream>>>();
    hist_kernel<<<eblocks, blk, 0, stream>>>(row);
    scan_kernel<<<1, dim3(1024), 0, stream>>>();
    scatter_kernel<<<eblocks, blk, 0, stream>>>(row, col);

    input_proj_kernel<<<kN / NPB, blk, 0, stream>>>(x, enc_in_W, enc_in_b, clf_in_W, clf_in_b);

    // ---- encoder GIN stack (unweighted) ----
    for (int l = 0; l < 3; l++) {
        agg_csr_kernel<<<kN / 2, blk, 0, stream>>>(0, 0);
        gin_mlp_kernel<<<kN / NPB, blk, 0, stream>>>(
            0,
            enc_W1 + (size_t)l * kD * kH, enc_b1 + (size_t)l * kH,
            enc_W2 + (size_t)l * kH * kD, enc_b2 + (size_t)l * kD, (l < 2) ? 1 : 0);
    }

    // ---- edge attention ----
    att_dense_kernel<<<kN / NPB, blk, 0, stream>>>(0, att_W1, att_b1);
    att_dense_kernel<<<kN / NPB, blk, 0, stream>>>(1, att_W1 + (size_t)kD * kA4, nullptr);
    att_edge_kernel<<<kE / 4, blk, 0, stream>>>(row, col, att_W2, att_b2);
    att_permute_kernel<<<eblocks, blk, 0, stream>>>();

    // ---- classifier GIN stack (edge-weighted) ----
    for (int l = 0; l < 3; l++) {
        agg_csr_kernel<<<kN / 2, blk, 0, stream>>>(1, 1);
        gin_mlp_kernel<<<kN / NPB, blk, 0, stream>>>(
            1,
            clf_W1 + (size_t)l * kD * kH, clf_b1 + (size_t)l * kH,
            clf_W2 + (size_t)l * kH * kD, clf_b2 + (size_t)l * kD, (l < 2) ? 1 : 0);
    }

    // ---- mean pool + head ----
    pool_kernel<<<kN / PCHUNK, dim3(128), 0, stream>>>(batch);
    head_kernel<<<1, dim3(kG * kOUT), 0, stream>>>(head_W, head_b, out);
}

// Round 3
// 891.020 us; speedup vs baseline: 3.8756x; 2.3404x over previous
//
#include <hip/hip_runtime.h>
#include <hip/hip_bf16.h>
#include <cstddef>

#define kN 50000
#define kNP 50048   // padded to 64*782
#define kE 500000
#define kG 64
#define kDIN 64
#define kD 128
#define kH 256   // 2*D
#define kA4 512  // 4*D
#define kOUT 10
#define NPB 16
#define PCHUNK 200

typedef __attribute__((ext_vector_type(8))) short bfrag_t;
typedef __attribute__((ext_vector_type(4))) float f32x4;
union FragCast { uint4 u; bfrag_t f; };

// ---- static device scratch (device globals; .bss zero on load, rewritten per call) ----
__device__ __attribute__((aligned(16))) __hip_bfloat16 g_h [(size_t)kNP * kD];
__device__ __attribute__((aligned(16))) __hip_bfloat16 g_hc[(size_t)kNP * kD];
__device__ __attribute__((aligned(16))) __hip_bfloat16 g_z [(size_t)kNP * kD];
__device__ __attribute__((aligned(16))) __hip_bfloat16 g_A [(size_t)kNP * kA4];
__device__ __attribute__((aligned(16))) __hip_bfloat16 g_B [(size_t)kNP * kA4];
__device__ __attribute__((aligned(16))) __hip_bfloat16 g_pk[1024 * 512];  // packed MFMA B-frags
__device__ float g_att [kE];
__device__ float g_atts[kE];
__device__ int   g_rowptr[kN + 1];
__device__ int   g_cnt[kN];
__device__ int   g_cols[kE];
__device__ int   g_eid [kE];
__device__ float g_pool[kG * kD];
__device__ float g_gcnt[kG];

__device__ inline float bflo(unsigned u) { union { unsigned i; float f; } c; c.i = u << 16; return c.f; }
__device__ inline float bfhi(unsigned u) { union { unsigned i; float f; } c; c.i = u & 0xffff0000u; return c.f; }

// ---- weight prepack: fp32 -> bf16 MFMA B-fragment order ----
// matrices: [0..2] encW1(128x256) [3..5] encW2(256x128) [6..8] clfW1 [9..11] clfW2
//           [12] attTop(128x512) [13] attBot(128x512)
// B-frag (k0,n0): lane holds B[k0*32+(lane>>4)*8+j][n0*16+(lane&15)], j=0..7.
struct SrcPtrs { const float* p[14]; };

__global__ __launch_bounds__(64) void prepack_kernel(SrcPtrs sp) {
    const int fs[15] = {0,64,128,192,256,320,384,448,512,576,640,704,768,896,1024};
    const int Ns[14] = {256,256,256,128,128,128,256,256,256,128,128,128,512,512};
    int f = blockIdx.x;
    int m = 0;
    while (f >= fs[m + 1]) m++;
    const int fl = f - fs[m];
    const int N = Ns[m];
    const int n0 = fl % (N >> 4);
    const int k0 = fl / (N >> 4);
    const int lane = threadIdx.x;
    const int q = lane >> 4, c = lane & 15;
    const float* src = sp.p[m];
    __hip_bfloat16* dst = g_pk + (size_t)f * 512 + lane * 8;
    const int kb = k0 * 32 + q * 8;
    const int n = n0 * 16 + c;
#pragma unroll
    for (int j = 0; j < 8; j++)
        dst[j] = __float2bfloat16(src[(size_t)(kb + j) * N + n]);
}

// packed offsets (in bf16 elements)
#define PK_ENC_W1(l) ((size_t)(0   + (l) * 64) * 512)
#define PK_ENC_W2(l) ((size_t)(192 + (l) * 64) * 512)
#define PK_CLF_W1(l) ((size_t)(384 + (l) * 64) * 512)
#define PK_CLF_W2(l) ((size_t)(576 + (l) * 64) * 512)

__global__ __launch_bounds__(256) void zero_prep_kernel() {
    const int i = blockIdx.x * 256 + threadIdx.x;
    if (i < kN) g_cnt[i] = 0;
    if (i < kG * kD) g_pool[i] = 0.f;
    if (i < kG) g_gcnt[i] = 0.f;
    if (i < (kNP - kN) * kD) g_z[(size_t)kN * kD + i] = __float2bfloat16(0.f);  // pad rows
}

__global__ __launch_bounds__(256) void hist_kernel(const int* __restrict__ row) {
    const int e = blockIdx.x * 256 + threadIdx.x;
    if (e < kE) atomicAdd(&g_cnt[row[e]], 1);
}

__global__ __launch_bounds__(1024) void scan_kernel() {
    const int t = threadIdx.x;
    const int base_i = t * 49;
    int local[49];
    int s = 0;
    for (int i = 0; i < 49; i++) {
        const int idx = base_i + i;
        const int c = (idx < kN) ? g_cnt[idx] : 0;
        local[i] = s;
        s += c;
    }
    __shared__ int part[1024];
    part[t] = s;
    __syncthreads();
    for (int off = 1; off < 1024; off <<= 1) {
        int v = 0;
        if (t >= off) v = part[t - off];
        __syncthreads();
        part[t] += v;
        __syncthreads();
    }
    const int base = (t == 0) ? 0 : part[t - 1];
    for (int i = 0; i < 49; i++) {
        const int idx = base_i + i;
        if (idx < kN) {
            const int v = base + local[i];
            g_rowptr[idx] = v;
            g_cnt[idx] = v;
        }
    }
    if (t == 1023) g_rowptr[kN] = kE;
}

__global__ __launch_bounds__(256) void scatter_kernel(
    const int* __restrict__ row, const int* __restrict__ col) {
    const int e = blockIdx.x * 256 + threadIdx.x;
    if (e >= kE) return;
    const int r = row[e];
    const int pos = atomicAdd(&g_cnt[r], 1);
    g_cols[pos] = col[e];
    g_eid[pos] = e;
}

__global__ __launch_bounds__(256) void att_permute_kernel() {
    const int i = blockIdx.x * 256 + threadIdx.x;
    if (i < kE) g_atts[i] = g_att[g_eid[i]];
}

// h = relu(x @ eW + eb) -> g_h (bf16), hc likewise -> g_hc.
__global__ __launch_bounds__(256) void input_proj_kernel(
    const float* __restrict__ x,
    const float* __restrict__ eW, const float* __restrict__ eb,
    const float* __restrict__ cW, const float* __restrict__ cb) {
    __shared__ float xs[NPB][kDIN];
    const int node0 = blockIdx.x * NPB;
    const int t = threadIdx.x;
    for (int i = t; i < NPB * kDIN; i += 256)
        xs[i >> 6][i & 63] = x[(size_t)node0 * kDIN + i];
    __syncthreads();
    const int j = t & 127, half = t >> 7;
    const float* W = half ? cW : eW;
    const float bias = half ? cb[j] : eb[j];
    float acc[NPB];
#pragma unroll
    for (int n = 0; n < NPB; n++) acc[n] = bias;
    for (int k = 0; k < kDIN; k++) {
        float w = W[k * kD + j];
#pragma unroll
        for (int n = 0; n < NPB; n++) acc[n] = fmaf(xs[n][k], w, acc[n]);
    }
    __hip_bfloat16* outp = half ? g_hc : g_h;
#pragma unroll
    for (int n = 0; n < NPB; n++)
        outp[(size_t)(node0 + n) * kD + j] = __float2bfloat16(fmaxf(acc[n], 0.f));
}

// CSR aggregation (bf16): z[n] = h[n] + sum_j h[col[j]] * att?; 8 nodes/block, 32 lanes/node.
__global__ __launch_bounds__(256) void agg_csr_kernel(int src_hc, int use_att) {
    const int t = threadIdx.x;
    const int node = blockIdx.x * 8 + (t >> 5);
    const int dp = t & 31;  // uint2 index: dims 4dp..4dp+3
    const uint2* __restrict__ src = (const uint2*)(src_hc ? g_hc : g_h);
    const int beg = g_rowptr[node], end = g_rowptr[node + 1];
    uint2 sv = src[(size_t)node * 32 + dp];
    float a0 = bflo(sv.x), a1 = bfhi(sv.x), a2 = bflo(sv.y), a3 = bfhi(sv.y);
    if (use_att) {
        for (int j = beg; j < end; j++) {
            uint2 v = src[(size_t)g_cols[j] * 32 + dp];
            float wt = g_atts[j];
            a0 = fmaf(bflo(v.x), wt, a0);
            a1 = fmaf(bfhi(v.x), wt, a1);
            a2 = fmaf(bflo(v.y), wt, a2);
            a3 = fmaf(bfhi(v.y), wt, a3);
        }
    } else {
        for (int j = beg; j < end; j++) {
            uint2 v = src[(size_t)g_cols[j] * 32 + dp];
            a0 += bflo(v.x); a1 += bfhi(v.x); a2 += bflo(v.y); a3 += bfhi(v.y);
        }
    }
    union { uint2 u; __hip_bfloat16 h[4]; } o;
    o.h[0] = __float2bfloat16(a0); o.h[1] = __float2bfloat16(a1);
    o.h[2] = __float2bfloat16(a2); o.h[3] = __float2bfloat16(a3);
    ((uint2*)g_z)[(size_t)node * 32 + dp] = o.u;
}

// MFMA GIN MLP: h = [relu]( relu(z @ W1 + b1) @ W2 + b2 ). 64 nodes/block, 4 waves.
// C/D layout (m89): col=lane&15, row=(lane>>4)*4+r. A layout: A[m=lane&15][k=(lane>>4)*8+j].
__global__ __launch_bounds__(256) void gin_mlp_mfma(
    int h_sel, size_t pkW1off, size_t pkW2off,
    const float* __restrict__ b1, const float* __restrict__ b2, int relu_out) {
    __shared__ __hip_bfloat16 zs[64][136];   // z tile / out tile (pad: 272B row, +4 banks/row)
    __shared__ __hip_bfloat16 hid[64][264];  // hidden tile
    const int t = threadIdx.x;
    const int lane = t & 63, w = t >> 6;
    const int node0 = blockIdx.x * 64;
    __hip_bfloat16* hp = h_sel ? g_hc : g_h;

    {   // stage z tile (coalesced b128)
        const uint4* src = (const uint4*)(g_z + (size_t)node0 * kD);
#pragma unroll
        for (int it = 0; it < 4; it++) {
            int idx = t + it * 256;
            int r = idx >> 4, c = idx & 15;
            *(uint4*)(&zs[r][c * 8]) = src[(size_t)r * 16 + c];
        }
    }
    __syncthreads();

    const int q = lane >> 4, cidx = lane & 15;

    // GEMM1: [64x128]@[128x256]; wave w owns cols [w*64, w*64+64)
    f32x4 acc1[4][4] = {};
    const uint4* pk1 = (const uint4*)(g_pk + pkW1off);
    for (int k0 = 0; k0 < 4; k0++) {
        FragCast a[4], b[4];
#pragma unroll
        for (int mt = 0; mt < 4; mt++)
            a[mt].u = *(const uint4*)(&zs[mt * 16 + cidx][k0 * 32 + q * 8]);
#pragma unroll
        for (int nt = 0; nt < 4; nt++)
            b[nt].u = pk1[(size_t)(k0 * 16 + (w * 4 + nt)) * 64 + lane];
#pragma unroll
        for (int mt = 0; mt < 4; mt++)
#pragma unroll
            for (int nt = 0; nt < 4; nt++)
                acc1[mt][nt] = __builtin_amdgcn_mfma_f32_16x16x32_bf16(
                    a[mt].f, b[nt].f, acc1[mt][nt], 0, 0, 0);
    }
#pragma unroll
    for (int nt = 0; nt < 4; nt++) {
        const int col = w * 64 + nt * 16 + cidx;
        const float bv = b1[col];
#pragma unroll
        for (int mt = 0; mt < 4; mt++)
#pragma unroll
            for (int r = 0; r < 4; r++)
                hid[mt * 16 + q * 4 + r][col] =
                    __float2bfloat16(fmaxf(acc1[mt][nt][r] + bv, 0.f));
    }
    __syncthreads();

    // GEMM2: [64x256]@[256x128]; wave w owns cols [w*32, w*32+32)
    f32x4 acc2[4][2] = {};
    const uint4* pk2 = (const uint4*)(g_pk + pkW2off);
    for (int k0 = 0; k0 < 8; k0++) {
        FragCast a[4], b[2];
#pragma unroll
        for (int mt = 0; mt < 4; mt++)
            a[mt].u = *(const uint4*)(&hid[mt * 16 + cidx][k0 * 32 + q * 8]);
#pragma unroll
        for (int nt = 0; nt < 2; nt++)
            b[nt].u = pk2[(size_t)(k0 * 8 + (w * 2 + nt)) * 64 + lane];
#pragma unroll
        for (int mt = 0; mt < 4; mt++)
#pragma unroll
            for (int nt = 0; nt < 2; nt++)
                acc2[mt][nt] = __builtin_amdgcn_mfma_f32_16x16x32_bf16(
                    a[mt].f, b[nt].f, acc2[mt][nt], 0, 0, 0);
    }
    // epilogue2 -> zs reused as out tile [64][128]
#pragma unroll
    for (int nt = 0; nt < 2; nt++) {
        const int col = w * 32 + nt * 16 + cidx;
        const float bv = b2[col];
#pragma unroll
        for (int mt = 0; mt < 4; mt++)
#pragma unroll
            for (int r = 0; r < 4; r++) {
                float v = acc2[mt][nt][r] + bv;
                if (relu_out) v = fmaxf(v, 0.f);
                zs[mt * 16 + q * 4 + r][col] = __float2bfloat16(v);
            }
    }
    __syncthreads();
    {   // coalesced copy-out
        uint4* dst = (uint4*)(hp + (size_t)node0 * kD);
#pragma unroll
        for (int it = 0; it < 4; it++) {
            int idx = t + it * 256;
            int r = idx >> 4, c = idx & 15;
            dst[(size_t)r * 16 + c] = *(const uint4*)(&zs[r][c * 8]);
        }
    }
}

// A/B = h @ attW1_{top,bot} (+b1 for A); grid (782, 4): y = mat*2 + half(256 cols).
__global__ __launch_bounds__(256) void att_dense_mfma(const float* __restrict__ b1) {
    __shared__ __hip_bfloat16 zs[64][136];
    __shared__ __hip_bfloat16 ob[64][264];
    const int t = threadIdx.x;
    const int lane = t & 63, w = t >> 6;
    const int node0 = blockIdx.x * 64;
    const int mat = blockIdx.y >> 1, half = blockIdx.y & 1;
    __hip_bfloat16* outp = mat ? g_B : g_A;
    const size_t pkoff = (size_t)(mat ? 896 : 768) * 512;

    const uint4* src = (const uint4*)(g_h + (size_t)node0 * kD);
#pragma unroll
    for (int it = 0; it < 4; it++) {
        int idx = t + it * 256;
        int r = idx >> 4, c = idx & 15;
        *(uint4*)(&zs[r][c * 8]) = src[(size_t)r * 16 + c];
    }
    __syncthreads();

    const int q = lane >> 4, cidx = lane & 15;
    f32x4 acc[4][4] = {};
    const uint4* pk = (const uint4*)(g_pk + pkoff);
    for (int k0 = 0; k0 < 4; k0++) {
        FragCast a[4], b[4];
#pragma unroll
        for (int mt = 0; mt < 4; mt++)
            a[mt].u = *(const uint4*)(&zs[mt * 16 + cidx][k0 * 32 + q * 8]);
#pragma unroll
        for (int nt = 0; nt < 4; nt++)
            b[nt].u = pk[(size_t)(k0 * 32 + (half * 16 + w * 4 + nt)) * 64 + lane];
#pragma unroll
        for (int mt = 0; mt < 4; mt++)
#pragma unroll
            for (int nt = 0; nt < 4; nt++)
                acc[mt][nt] = __builtin_amdgcn_mfma_f32_16x16x32_bf16(
                    a[mt].f, b[nt].f, acc[mt][nt], 0, 0, 0);
    }
#pragma unroll
    for (int nt = 0; nt < 4; nt++) {
        const int lcol = w * 64 + nt * 16 + cidx;
        const float bv = (mat == 0) ? b1[half * 256 + lcol] : 0.f;
#pragma unroll
        for (int mt = 0; mt < 4; mt++)
#pragma unroll
            for (int r = 0; r < 4; r++)
                ob[mt * 16 + q * 4 + r][lcol] = __float2bfloat16(acc[mt][nt][r] + bv);
    }
    __syncthreads();
    uint4* dst = (uint4*)(outp + (size_t)node0 * kA4 + half * 256);
#pragma unroll
    for (int it = 0; it < 8; it++) {
        int idx = t + it * 256;
        int r = idx >> 5, c = idx & 31;
        dst[(size_t)r * 64 + c] = *(const uint4*)(&ob[r][c * 8]);
    }
}

// att[e] = sigmoid( relu(A[row]+B[col]) . W2 + b2 ); one 64-lane wave per edge.
__global__ __launch_bounds__(256) void att_edge_kernel(
    const int* __restrict__ row, const int* __restrict__ col,
    const float* __restrict__ W2, const float* __restrict__ b2) {
    const int e = blockIdx.x * 4 + (threadIdx.x >> 6);
    const int lane = threadIdx.x & 63;
    const int m0 = lane * 8;
    const uint4 au = *(const uint4*)(g_A + (size_t)row[e] * kA4 + m0);
    const uint4 bu = *(const uint4*)(g_B + (size_t)col[e] * kA4 + m0);
    const float4 w0 = *(const float4*)(W2 + m0);
    const float4 w1 = *(const float4*)(W2 + m0 + 4);
    float s = 0.f;
    s = fmaf(fmaxf(bflo(au.x) + bflo(bu.x), 0.f), w0.x, s);
    s = fmaf(fmaxf(bfhi(au.x) + bfhi(bu.x), 0.f), w0.y, s);
    s = fmaf(fmaxf(bflo(au.y) + bflo(bu.y), 0.f), w0.z, s);
    s = fmaf(fmaxf(bfhi(au.y) + bfhi(bu.y), 0.f), w0.w, s);
    s = fmaf(fmaxf(bflo(au.z) + bflo(bu.z), 0.f), w1.x, s);
    s = fmaf(fmaxf(bfhi(au.z) + bfhi(bu.z), 0.f), w1.y, s);
    s = fmaf(fmaxf(bflo(au.w) + bflo(bu.w), 0.f), w1.z, s);
    s = fmaf(fmaxf(bfhi(au.w) + bfhi(bu.w), 0.f), w1.w, s);
    for (int off = 32; off > 0; off >>= 1) s += __shfl_down(s, off);
    if (lane == 0) {
        const float logit = s + b2[0];
        g_att[e] = 1.f / (1.f + __expf(-logit));
    }
}

// Segmented mean-pool accumulate over sorted batch; 64 threads = 2 dims each.
__global__ __launch_bounds__(64) void pool_kernel(const int* __restrict__ batch) {
    const int t = threadIdx.x;
    int n = blockIdx.x * PCHUNK;
    const int nend = n + PCHUNK;
    const unsigned* __restrict__ hc = (const unsigned*)g_hc;
    int gcur = batch[n];
    float a0 = 0.f, a1 = 0.f, cv = 0.f;
    for (; n < nend; n++) {
        const int g = batch[n];
        if (g != gcur) {
            atomicAdd(&g_pool[gcur * kD + 2 * t], a0);
            atomicAdd(&g_pool[gcur * kD + 2 * t + 1], a1);
            if (t == 0) atomicAdd(&g_gcnt[gcur], cv);
            a0 = a1 = cv = 0.f; gcur = g;
        }
        unsigned v = hc[(size_t)n * 64 + t];
        a0 += bflo(v); a1 += bfhi(v);
        cv += 1.f;
    }
    atomicAdd(&g_pool[gcur * kD + 2 * t], a0);
    atomicAdd(&g_pool[gcur * kD + 2 * t + 1], a1);
    if (t == 0) atomicAdd(&g_gcnt[gcur], cv);
}

__global__ __launch_bounds__(640) void head_kernel(
    const float* __restrict__ hW, const float* __restrict__ hb,
    float* __restrict__ out) {
    const int t = threadIdx.x;
    const int g = t / kOUT, o = t - g * kOUT;
    const float c = fmaxf(g_gcnt[g], 1.f);
    const float inv = 1.f / c;
    float acc = hb[o];
    for (int k = 0; k < kD; k++)
        acc = fmaf(g_pool[g * kD + k] * inv, hW[k * kOUT + o], acc);
    out[(size_t)g * kOUT + o] = acc;
}

extern "C" void kernel_launch(void* const* d_in, const int* in_sizes, int n_in,
                              void* d_out, int out_size, void* d_ws, size_t ws_size,
                              hipStream_t stream) {
    const float* x        = (const float*)d_in[0];
    const int*   ei       = (const int*)d_in[1];
    const int*   row      = ei;
    const int*   col      = ei + kE;
    const int*   batch    = (const int*)d_in[2];
    const float* enc_in_W = (const float*)d_in[4];
    const float* enc_in_b = (const float*)d_in[5];
    const float* enc_W1   = (const float*)d_in[6];
    const float* enc_b1   = (const float*)d_in[7];
    const float* enc_W2   = (const float*)d_in[8];
    const float* enc_b2   = (const float*)d_in[9];
    const float* att_W1   = (const float*)d_in[10];
    const float* att_b1   = (const float*)d_in[11];
    const float* att_W2   = (const float*)d_in[12];
    const float* att_b2   = (const float*)d_in[13];
    const float* clf_in_W = (const float*)d_in[14];
    const float* clf_in_b = (const float*)d_in[15];
    const float* clf_W1   = (const float*)d_in[16];
    const float* clf_b1   = (const float*)d_in[17];
    const float* clf_W2   = (const float*)d_in[18];
    const float* clf_b2   = (const float*)d_in[19];
    const float* head_W   = (const float*)d_in[20];
    const float* head_b   = (const float*)d_in[21];
    float* out = (float*)d_out;

    const dim3 blk(256);
    const int eblocks = (kE + 255) / 256;

    // ---- weight prepack (bf16 fragment order) ----
    SrcPtrs sp;
    for (int l = 0; l < 3; l++) {
        sp.p[0 + l] = enc_W1 + (size_t)l * kD * kH;
        sp.p[3 + l] = enc_W2 + (size_t)l * kH * kD;
        sp.p[6 + l] = clf_W1 + (size_t)l * kD * kH;
        sp.p[9 + l] = clf_W2 + (size_t)l * kH * kD;
    }
    sp.p[12] = att_W1;                       // rows 0..127 (h[row] part)
    sp.p[13] = att_W1 + (size_t)kD * kA4;    // rows 128..255 (h[col] part)
    prepack_kernel<<<1024, dim3(64), 0, stream>>>(sp);

    // ---- CSR build ----
    zero_prep_kernel<<<(kNP + 255) / 256, blk, 0, stream>>>();
    hist_kernel<<<eblocks, blk, 0, stream>>>(row);
    scan_kernel<<<1, dim3(1024), 0, stream>>>();
    scatter_kernel<<<eblocks, blk, 0, stream>>>(row, col);

    input_proj_kernel<<<kN / NPB, blk, 0, stream>>>(x, enc_in_W, enc_in_b, clf_in_W, clf_in_b);

    // ---- encoder GIN stack ----
    for (int l = 0; l < 3; l++) {
        agg_csr_kernel<<<kN / 8, blk, 0, stream>>>(0, 0);
        gin_mlp_mfma<<<kNP / 64, blk, 0, stream>>>(
            0, PK_ENC_W1(l), PK_ENC_W2(l),
            enc_b1 + (size_t)l * kH, enc_b2 + (size_t)l * kD, (l < 2) ? 1 : 0);
    }

    // ---- edge attention ----
    att_dense_mfma<<<dim3(kNP / 64, 4), blk, 0, stream>>>(att_b1);
    att_edge_kernel<<<kE / 4, blk, 0, stream>>>(row, col, att_W2, att_b2);
    att_permute_kernel<<<eblocks, blk, 0, stream>>>();

    // ---- classifier GIN stack (edge-weighted) ----
    for (int l = 0; l < 3; l++) {
        agg_csr_kernel<<<kN / 8, blk, 0, stream>>>(1, 1);
        gin_mlp_mfma<<<kNP / 64, blk, 0, stream>>>(
            1, PK_CLF_W1(l), PK_CLF_W2(l),
            clf_b1 + (size_t)l * kH, clf_b2 + (size_t)l * kD, (l < 2) ? 1 : 0);
    }

    // ---- mean pool + head ----
    pool_kernel<<<kN / PCHUNK, dim3(64), 0, stream>>>(batch);
    head_kernel<<<1, dim3(kG * kOUT), 0, stream>>>(head_W, head_b, out);
}